// Round 3
// baseline (122.566 us; speedup 1.0000x reference)
//
#include <hip/hip_runtime.h>

// SparseNeuralNetwork: 256 independent sub-nets j = i*16 + o (i,o in [0,16)).
//   layer0: v[k] = relu(W0[16j+k, i] * x[b,i] + b0[16j+k]),   k in [0,16)
//   layer1: u[m] = relu(b1[8j+m] + sum_k W1[8j+m, 16j+k] * v[k]), m in [0,8)
//   out[b,o] = b2[o] + sum_i sum_m W2[o, 8j+m] * u[m]
//
// R3: weights are wave-uniform (lanes vary only batch), so route them through
// the SCALAR pipe instead of LDS broadcast (R2 was LDS-issue-bound: 704
// ds_read_b128/wave x 12cyc vs 11K VALU cyc/SIMD). A pack pre-kernel gathers
// the 176 live weights per (o,i) into one contiguous 192-float slot in d_ws;
// the main kernel streams them as s_load_dwordx16 from a uniform pointer.
// No LDS at all. Target: VALU-bound ~5-6 us (318M fp32 FMA, 78.6 T FMA/s).

#define BATCH   8192
#define IN_DIM  16
#define OUT_DIM 16
#define H0      16
#define H1      8
#define D0      (IN_DIM * OUT_DIM * H0)   // 4096
#define D1      (IN_DIM * OUT_DIM * H1)   // 2048
#define PACK_STRIDE 192                    // 176 floats used, 64B-aligned slots

// Packed slot layout, slot = o*16+i (j = i*16+o):
//   [0..15]    W0[(j*16+k)*16 + i]          (layer0 weights, col i)
//   [16..31]   b0[j*16+k]
//   [32..159]  W1[(j*8+m)*4096 + j*16+k]    (m-major, 8 rows x 16)
//   [160..167] b1[j*8+m]
//   [168..175] W2[o*2048 + j*8+m]
__global__ void pack_kernel(const float* __restrict__ W0, const float* __restrict__ b0,
                            const float* __restrict__ W1, const float* __restrict__ b1,
                            const float* __restrict__ W2, float* __restrict__ pack)
{
    const int oi = blockIdx.x;            // o*16 + i
    const int o  = oi >> 4, i = oi & 15;
    const int j  = i * 16 + o;
    const int t  = threadIdx.x;
    float val = 0.0f;
    if      (t < 16)  val = W0[(j * H0 + t) * IN_DIM + i];
    else if (t < 32)  val = b0[j * H0 + (t - 16)];
    else if (t < 160) { const int m = (t - 32) >> 4, k = (t - 32) & 15;
                        val = W1[(size_t)(j * H1 + m) * D0 + j * H0 + k]; }
    else if (t < 168) val = b1[j * H1 + (t - 160)];
    else if (t < 176) val = W2[o * D1 + j * H1 + (t - 168)];
    if (t < 176) pack[oi * PACK_STRIDE + t] = val;
}

__global__ __launch_bounds__(256) void sparse_mlp_kernel(
    const float* __restrict__ x,
    const float* __restrict__ b2,
    const float* __restrict__ pack,
    float* __restrict__ out)
{
    const int lane = threadIdx.x & 63;
    const int wv   = threadIdx.x >> 6;
    const int b    = blockIdx.x * 64 + lane;
    // o wave-uniform -> every pack address is wave-uniform -> s_load
    const int o    = __builtin_amdgcn_readfirstlane((int)(blockIdx.y * 4 + wv));

    // x[b, 0..15] -> registers, coalesced 64 B per lane
    float xr[16];
    {
        const float4* xp = (const float4*)(x + (size_t)b * IN_DIM);
        float4 a0 = xp[0], a1 = xp[1], a2 = xp[2], a3 = xp[3];
        xr[0]=a0.x; xr[1]=a0.y; xr[2]=a0.z;  xr[3]=a0.w;
        xr[4]=a1.x; xr[5]=a1.y; xr[6]=a1.z;  xr[7]=a1.w;
        xr[8]=a2.x; xr[9]=a2.y; xr[10]=a2.z; xr[11]=a2.w;
        xr[12]=a3.x;xr[13]=a3.y;xr[14]=a3.z; xr[15]=a3.w;
    }

    float acc = b2[o];

    #pragma unroll
    for (int i = 0; i < IN_DIM; ++i) {
        const float* __restrict__ wp = pack + (size_t)(o * 16 + i) * PACK_STRIDE;
        const float xi = xr[i];

        float v[H0];
        #pragma unroll
        for (int k = 0; k < H0; ++k)
            v[k] = fmaxf(fmaf(wp[k], xi, wp[16 + k]), 0.0f);

        #pragma unroll
        for (int m = 0; m < H1; ++m) {
            float u = wp[160 + m];
            #pragma unroll
            for (int k = 0; k < H0; ++k)
                u = fmaf(wp[32 + m * 16 + k], v[k], u);
            acc = fmaf(wp[168 + m], fmaxf(u, 0.0f), acc);
        }
    }

    out[(size_t)b * OUT_DIM + o] = acc;
}

extern "C" void kernel_launch(void* const* d_in, const int* in_sizes, int n_in,
                              void* d_out, int out_size, void* d_ws, size_t ws_size,
                              hipStream_t stream) {
    const float* x  = (const float*)d_in[0];
    const float* W0 = (const float*)d_in[1];
    const float* b0 = (const float*)d_in[2];
    const float* W1 = (const float*)d_in[3];
    const float* b1 = (const float*)d_in[4];
    const float* W2 = (const float*)d_in[5];
    const float* b2 = (const float*)d_in[6];
    float* out  = (float*)d_out;
    float* pack = (float*)d_ws;           // 256 * 192 * 4 = 196 KB << ws_size

    pack_kernel<<<256, 192, 0, stream>>>(W0, b0, W1, b1, W2, pack);

    dim3 grid(BATCH / 64, OUT_DIM / 4);   // 128 x 4 = 512 blocks, 2048 waves
    sparse_mlp_kernel<<<grid, 256, 0, stream>>>(x, b2, pack, out);
}

// Round 4
// 99.913 us; speedup vs baseline: 1.2267x; 1.2267x over previous
//
#include <hip/hip_runtime.h>

// SparseNeuralNetwork: 256 independent sub-nets j = i*16 + o (i,o in [0,16)).
//   layer0: v[k] = relu(W0[16j+k, i] * x[b,i] + b0[16j+k]),   k in [0,16)
//   layer1: u[m] = relu(b1[8j+m] + sum_k W1[8j+m, 16j+k] * v[k]), m in [0,8)
//   out[b,o] = b2[o] + sum_i sum_m W2[o, 8j+m] * u[m]
//
// R4: R3's scalar-pipe weight path was right (weights wave-uniform -> SMEM,
// VALU does pure v_fmac v,s,v) but latency-exposed at 2 waves/SIMD. Split the
// i-loop 4-way: wave = (b64, o, igroup), 8192 waves = 32/CU, so SGPR-chunk
// lgkmcnt waits are hidden by TLP. 4 partials reduced via 1 KB LDS per block.
// Target: VALU-bound ~5 us (318M fp32 FMA at 78.6 T FMA/s).

#define BATCH   8192
#define IN_DIM  16
#define OUT_DIM 16
#define H0      16
#define H1      8
#define D0      (IN_DIM * OUT_DIM * H0)   // 4096
#define D1      (IN_DIM * OUT_DIM * H1)   // 2048
#define PACK_STRIDE 192                    // 176 floats used, 64B-aligned slots

// Packed slot layout, slot = o*16+i (j = i*16+o):
//   [0..15]    W0[(j*16+k)*16 + i]          (layer0 weights, col i)
//   [16..31]   b0[j*16+k]
//   [32..159]  W1[(j*8+m)*4096 + j*16+k]    (m-major, 8 rows x 16)
//   [160..167] b1[j*8+m]
//   [168..175] W2[o*2048 + j*8+m]
__global__ void pack_kernel(const float* __restrict__ W0, const float* __restrict__ b0,
                            const float* __restrict__ W1, const float* __restrict__ b1,
                            const float* __restrict__ W2, float* __restrict__ pack)
{
    const int oi = blockIdx.x;            // o*16 + i
    const int o  = oi >> 4, i = oi & 15;
    const int j  = i * 16 + o;
    const int t  = threadIdx.x;
    float val = 0.0f;
    if      (t < 16)  val = W0[(j * H0 + t) * IN_DIM + i];
    else if (t < 32)  val = b0[j * H0 + (t - 16)];
    else if (t < 160) { const int m = (t - 32) >> 4, k = (t - 32) & 15;
                        val = W1[(size_t)(j * H1 + m) * D0 + j * H0 + k]; }
    else if (t < 168) val = b1[j * H1 + (t - 160)];
    else if (t < 176) val = W2[o * D1 + j * H1 + (t - 168)];
    if (t < 176) pack[oi * PACK_STRIDE + t] = val;
}

__global__ __launch_bounds__(256, 8) void sparse_mlp_kernel(
    const float* __restrict__ x,
    const float* __restrict__ b2,
    const float* __restrict__ pack,
    float* __restrict__ out)
{
    __shared__ float red[4][64];

    const int lane = threadIdx.x & 63;
    const int b    = blockIdx.x * 64 + lane;
    const int o    = blockIdx.y;                              // SGPR (uniform)
    // i-group: wave-uniform; pin to SGPR so all pack addresses scalarize
    const int ig   = __builtin_amdgcn_readfirstlane((int)(threadIdx.x >> 6));

    // this wave's 4 x-values: x[b, 4ig .. 4ig+3]
    const float4 xv = *(const float4*)(x + (size_t)b * IN_DIM + ig * 4);
    const float xr[4] = {xv.x, xv.y, xv.z, xv.w};

    float acc = (ig == 0) ? b2[o] : 0.0f;

    #pragma unroll
    for (int ii = 0; ii < 4; ++ii) {
        const int i = ig * 4 + ii;
        const float* __restrict__ wp = pack + (size_t)(o * 16 + i) * PACK_STRIDE;
        const float xi = xr[ii];

        float v[H0];
        #pragma unroll
        for (int k = 0; k < H0; ++k)
            v[k] = fmaxf(fmaf(wp[k], xi, wp[16 + k]), 0.0f);

        #pragma unroll
        for (int m = 0; m < H1; ++m) {
            float u = wp[160 + m];
            #pragma unroll
            for (int k = 0; k < H0; ++k)
                u = fmaf(wp[32 + m * 16 + k], v[k], u);
            acc = fmaf(wp[168 + m], fmaxf(u, 0.0f), acc);
        }
    }

    red[ig][lane] = acc;
    __syncthreads();
    if (ig == 0) {
        const float s = red[0][lane] + red[1][lane] + red[2][lane] + red[3][lane];
        out[(size_t)b * OUT_DIM + o] = s;
    }
}

extern "C" void kernel_launch(void* const* d_in, const int* in_sizes, int n_in,
                              void* d_out, int out_size, void* d_ws, size_t ws_size,
                              hipStream_t stream) {
    const float* x  = (const float*)d_in[0];
    const float* W0 = (const float*)d_in[1];
    const float* b0 = (const float*)d_in[2];
    const float* W1 = (const float*)d_in[3];
    const float* b1 = (const float*)d_in[4];
    const float* W2 = (const float*)d_in[5];
    const float* b2 = (const float*)d_in[6];
    float* out  = (float*)d_out;
    float* pack = (float*)d_ws;           // 256 * 192 * 4 = 196 KB << ws_size

    pack_kernel<<<256, 192, 0, stream>>>(W0, b0, W1, b1, W2, pack);

    dim3 grid(BATCH / 64, OUT_DIM);       // 128 x 16 = 2048 blocks, 8192 waves
    sparse_mlp_kernel<<<grid, 256, 0, stream>>>(x, b2, pack, out);
}

// Round 5
// 98.294 us; speedup vs baseline: 1.2469x; 1.0165x over previous
//
#include <hip/hip_runtime.h>

// SparseNeuralNetwork: 256 independent sub-nets j = i*16 + o (i,o in [0,16)).
//   layer0: v[k] = relu(W0[16j+k, i] * x[b,i] + b0[16j+k]),   k in [0,16)
//   layer1: u[m] = relu(b1[8j+m] + sum_k W1[8j+m, 16j+k] * v[k]), m in [0,8)
//   out[b,o] = b2[o] + sum_i sum_m W2[o, 8j+m] * u[m]
//
// R5: R2 (LDS broadcast) and R4 (scalar pipe) both plateau ~35 us kernel time
// with totally different delivery pipes -> the shared cost is weight-fetch
// instructions per FLOP. Fix: 2 batch elems per thread (each fetched weight
// feeds 2 FMAs), LDS delivery (no SMEM lgkmcnt(0) drain), direct staging from
// the original tensors (no pack kernel / extra launch), 4-way i-split keeps
// 4096 waves = 4/SIMD. Per-SIMD VALU ~11.3K cyc (~4.7 us) vs ~9K cyc LDS pipe
// per CU -> should finally be VALU-bound.

#define BATCH   8192
#define IN_DIM  16
#define OUT_DIM 16
#define H0      16
#define H1      8
#define D0      (IN_DIM * OUT_DIM * H0)   // 4096
#define D1      (IN_DIM * OUT_DIM * H1)   // 2048

// LDS slot layout per i (stride 192 floats, 768 B, float4-aligned):
//   [0..15]   W0[(j*16+k)*16 + i]
//   [16..31]  b0[j*16+k]
//   [32..159] W1[(j*8+m)*4096 + j*16+k]   (m-major)
//   [160..167] b1[j*8+m]
//   [168..175] W2[o*2048 + j*8+m]
__global__ __launch_bounds__(256) void sparse_mlp_kernel(
    const float* __restrict__ x,
    const float* __restrict__ W0, const float* __restrict__ b0,
    const float* __restrict__ W1, const float* __restrict__ b1,
    const float* __restrict__ W2, const float* __restrict__ b2,
    float* __restrict__ out)
{
    __shared__ float sW[16][192];        // 12 KB
    __shared__ float red[4][128];        // 2 KB

    const int t = threadIdx.x;
    const int o = blockIdx.y;            // wave-uniform

    // ---- stage this o's weight slice (16 i-slots x 176 floats) ----
    #pragma unroll
    for (int f = t; f < 16 * 176; f += 256) {
        const int i = f / 176, r = f % 176;
        const int j = i * 16 + o;
        float val;
        if      (r < 16)  val = W0[(j * H0 + r) * IN_DIM + i];
        else if (r < 32)  val = b0[j * H0 + (r - 16)];
        else if (r < 160) { const int m = (r - 32) >> 4, k = (r - 32) & 15;
                            val = W1[(size_t)(j * H1 + m) * D0 + j * H0 + k]; }
        else if (r < 168) val = b1[j * H1 + (r - 160)];
        else              val = W2[o * D1 + j * H1 + (r - 168)];
        sW[i][r] = val;
    }
    __syncthreads();

    // ---- compute: thread = (2 batch elems, o, i-group) ----
    const int lane = t & 63;
    const int ig   = __builtin_amdgcn_readfirstlane(t >> 6);   // 0..3
    const int b    = blockIdx.x * 128 + lane;                  // b and b+64

    const float4 xa = *(const float4*)(x + (size_t)b * IN_DIM + ig * 4);
    const float4 xb = *(const float4*)(x + (size_t)(b + 64) * IN_DIM + ig * 4);
    const float xra[4] = {xa.x, xa.y, xa.z, xa.w};
    const float xrb[4] = {xb.x, xb.y, xb.z, xb.w};

    float acc0 = 0.0f, acc1 = 0.0f;

    #pragma unroll
    for (int ii = 0; ii < 4; ++ii) {
        const int i = ig * 4 + ii;
        const float* __restrict__ wp = sW[i];

        float v0[H0], v1[H0];
        #pragma unroll
        for (int k = 0; k < H0; ++k) {
            const float w = wp[k], bb = wp[16 + k];
            v0[k] = fmaxf(fmaf(w, xra[ii], bb), 0.0f);
            v1[k] = fmaxf(fmaf(w, xrb[ii], bb), 0.0f);
        }

        #pragma unroll
        for (int m = 0; m < H1; ++m) {
            float u0 = wp[160 + m], u1 = u0;
            #pragma unroll
            for (int k = 0; k < H0; ++k) {
                const float w = wp[32 + m * 16 + k];
                u0 = fmaf(w, v0[k], u0);
                u1 = fmaf(w, v1[k], u1);
            }
            const float w2 = wp[168 + m];
            acc0 = fmaf(w2, fmaxf(u0, 0.0f), acc0);
            acc1 = fmaf(w2, fmaxf(u1, 0.0f), acc1);
        }
    }

    red[ig][lane]      = acc0;
    red[ig][64 + lane] = acc1;
    __syncthreads();

    if (ig == 0) {
        const float bias = b2[o];
        const float s0 = red[0][lane] + red[1][lane] + red[2][lane] + red[3][lane] + bias;
        const float s1 = red[0][64 + lane] + red[1][64 + lane] + red[2][64 + lane] + red[3][64 + lane] + bias;
        out[(size_t)b * OUT_DIM + o]        = s0;
        out[(size_t)(b + 64) * OUT_DIM + o] = s1;
    }
}

extern "C" void kernel_launch(void* const* d_in, const int* in_sizes, int n_in,
                              void* d_out, int out_size, void* d_ws, size_t ws_size,
                              hipStream_t stream) {
    const float* x  = (const float*)d_in[0];
    const float* W0 = (const float*)d_in[1];
    const float* b0 = (const float*)d_in[2];
    const float* W1 = (const float*)d_in[3];
    const float* b1 = (const float*)d_in[4];
    const float* W2 = (const float*)d_in[5];
    const float* b2 = (const float*)d_in[6];
    float* out = (float*)d_out;

    dim3 grid(BATCH / 128, OUT_DIM);      // 64 x 16 = 1024 blocks, 4096 waves
    sparse_mlp_kernel<<<grid, 256, 0, stream>>>(x, W0, b0, W1, b1, W2, b2, out);
}